// Round 2
// baseline (2496.474 us; speedup 1.0000x reference)
//
#include <hip/hip_runtime.h>
#include <hip/hip_bf16.h>
#include <math.h>

#define NB   8
#define LL   2048
#define DMAJ 1024
#define DMIN 512
#define RR   129
#define KREL 64

// ---------------------------------------------------------------------------
// Generic NN GEMM: C[M,N] = A[M,K] @ B[K,N], row-major, fp32.
// 64x64 tile, BK=16, 256 threads, 4x4 micro-tile. M%64==0, N%64==0, K%16==0.
// Batched via blockIdx.z with element strides sA/sB/sC.
// ---------------------------------------------------------------------------
__global__ __launch_bounds__(256) void gemm_nn(const float* __restrict__ A,
                                               const float* __restrict__ Bm,
                                               float* __restrict__ C,
                                               int M, int N, int K,
                                               size_t sA, size_t sB, size_t sC) {
    __shared__ float As[16][65];
    __shared__ float Bs[16][64];
    const int tid = threadIdx.x;
    const int tx = tid & 15, ty = tid >> 4;
    const int m0 = blockIdx.y * 64, n0 = blockIdx.x * 64;
    A  += (size_t)blockIdx.z * sA;
    Bm += (size_t)blockIdx.z * sB;
    C  += (size_t)blockIdx.z * sC;
    float c[4][4] = {};
    for (int k0 = 0; k0 < K; k0 += 16) {
        for (int idx = tid; idx < 1024; idx += 256) {
            int m = idx >> 4, k = idx & 15;
            As[k][m] = A[(size_t)(m0 + m) * K + k0 + k];
        }
        for (int idx = tid; idx < 1024; idx += 256) {
            int k = idx >> 6, n = idx & 63;
            Bs[k][n] = Bm[(size_t)(k0 + k) * N + n0 + n];
        }
        __syncthreads();
#pragma unroll
        for (int k = 0; k < 16; ++k) {
            float a[4], b[4];
#pragma unroll
            for (int i = 0; i < 4; ++i) a[i] = As[k][ty * 4 + i];
#pragma unroll
            for (int j = 0; j < 4; ++j) b[j] = Bs[k][tx * 4 + j];
#pragma unroll
            for (int i = 0; i < 4; ++i)
#pragma unroll
                for (int j = 0; j < 4; ++j)
                    c[i][j] += a[i] * b[j];
        }
        __syncthreads();
    }
#pragma unroll
    for (int i = 0; i < 4; ++i)
#pragma unroll
        for (int j = 0; j < 4; ++j)
            C[(size_t)(m0 + ty * 4 + i) * N + n0 + tx * 4 + j] = c[i][j];
}

// ---------------------------------------------------------------------------
// NT GEMM with N-bounds: C[M,N] = A[M,K] @ B[N,K]^T.  (for rel_scores, N=129)
// ---------------------------------------------------------------------------
__global__ __launch_bounds__(256) void gemm_nt_bounds(const float* __restrict__ A,
                                                      const float* __restrict__ Bm,
                                                      float* __restrict__ C,
                                                      int M, int N, int K) {
    __shared__ float As[16][65];
    __shared__ float Bs[16][65];
    const int tid = threadIdx.x;
    const int tx = tid & 15, ty = tid >> 4;
    const int m0 = blockIdx.y * 64, n0 = blockIdx.x * 64;
    float c[4][4] = {};
    for (int k0 = 0; k0 < K; k0 += 16) {
        for (int idx = tid; idx < 1024; idx += 256) {
            int m = idx >> 4, k = idx & 15;
            As[k][m] = A[(size_t)(m0 + m) * K + k0 + k];
        }
        for (int idx = tid; idx < 1024; idx += 256) {
            int n = idx >> 4, k = idx & 15;
            int ng = n0 + n;
            Bs[k][n] = (ng < N) ? Bm[(size_t)ng * K + k0 + k] : 0.f;
        }
        __syncthreads();
#pragma unroll
        for (int k = 0; k < 16; ++k) {
            float a[4], b[4];
#pragma unroll
            for (int i = 0; i < 4; ++i) a[i] = As[k][ty * 4 + i];
#pragma unroll
            for (int j = 0; j < 4; ++j) b[j] = Bs[k][tx * 4 + j];
#pragma unroll
            for (int i = 0; i < 4; ++i)
#pragma unroll
                for (int j = 0; j < 4; ++j)
                    c[i][j] += a[i] * b[j];
        }
        __syncthreads();
    }
#pragma unroll
    for (int i = 0; i < 4; ++i)
#pragma unroll
        for (int j = 0; j < 4; ++j) {
            int ng = n0 + tx * 4 + j;
            if (ng < N) C[(size_t)(m0 + ty * 4 + i) * N + ng] = c[i][j];
        }
}

// ---------------------------------------------------------------------------
// scores[b,m,n] = (q[b,m,:].k[b,n,:] + relS[b,m,clip(n-m)+64]) / sqrt(512)
// per-batch NT GEMM, 64x64 tile, fused rel-bias + scale epilogue.
// ---------------------------------------------------------------------------
__global__ __launch_bounds__(256) void scores_kernel(const float* __restrict__ q,
                                                     const float* __restrict__ kk,
                                                     const float* __restrict__ relS,
                                                     float* __restrict__ attn) {
    __shared__ float As[16][65];
    __shared__ float Bs[16][65];
    const int b = blockIdx.z;
    const float* A  = q  + (size_t)b * LL * DMIN;
    const float* Bm = kk + (size_t)b * LL * DMIN;
    const float* rS = relS + (size_t)b * LL * RR;
    float* C = attn + (size_t)b * LL * LL;
    const int tid = threadIdx.x;
    const int tx = tid & 15, ty = tid >> 4;
    const int m0 = blockIdx.y * 64, n0 = blockIdx.x * 64;
    float c[4][4] = {};
    for (int k0 = 0; k0 < DMIN; k0 += 16) {
        for (int idx = tid; idx < 1024; idx += 256) {
            int m = idx >> 4, k = idx & 15;
            As[k][m] = A[(size_t)(m0 + m) * DMIN + k0 + k];
        }
        for (int idx = tid; idx < 1024; idx += 256) {
            int n = idx >> 4, k = idx & 15;
            Bs[k][n] = Bm[(size_t)(n0 + n) * DMIN + k0 + k];
        }
        __syncthreads();
#pragma unroll
        for (int k = 0; k < 16; ++k) {
            float a[4], bv[4];
#pragma unroll
            for (int i = 0; i < 4; ++i) a[i] = As[k][ty * 4 + i];
#pragma unroll
            for (int j = 0; j < 4; ++j) bv[j] = Bs[k][tx * 4 + j];
#pragma unroll
            for (int i = 0; i < 4; ++i)
#pragma unroll
                for (int j = 0; j < 4; ++j)
                    c[i][j] += a[i] * bv[j];
        }
        __syncthreads();
    }
    const float scale = 0.044194173824159216f;  // 1/sqrt(512)
#pragma unroll
    for (int i = 0; i < 4; ++i) {
        int m = m0 + ty * 4 + i;
#pragma unroll
        for (int j = 0; j < 4; ++j) {
            int n = n0 + tx * 4 + j;
            int r = n - m;
            r = r < -KREL ? -KREL : (r > KREL ? KREL : r);
            r += KREL;
            C[(size_t)m * LL + n] = (c[i][j] + rS[(size_t)m * RR + r]) * scale;
        }
    }
}

// ---------------------------------------------------------------------------
// In-place row softmax over rows of length 2048.
// ---------------------------------------------------------------------------
__global__ __launch_bounds__(256) void softmax_kernel(float* __restrict__ attn) {
    __shared__ float buf[LL];
    __shared__ float red[4];
    const size_t row = blockIdx.x;
    float* p = attn + row * LL;
    const int tid = threadIdx.x;
    float m = -1e30f;
    for (int j = tid; j < LL; j += 256) {
        float v = p[j];
        buf[j] = v;
        m = fmaxf(m, v);
    }
#pragma unroll
    for (int o = 32; o; o >>= 1) m = fmaxf(m, __shfl_down(m, o, 64));
    if ((tid & 63) == 0) red[tid >> 6] = m;
    __syncthreads();
    m = fmaxf(fmaxf(red[0], red[1]), fmaxf(red[2], red[3]));
    __syncthreads();
    float s = 0.f;
    for (int j = tid; j < LL; j += 256) {
        float e = __expf(buf[j] - m);
        buf[j] = e;
        s += e;
    }
#pragma unroll
    for (int o = 32; o; o >>= 1) s += __shfl_down(s, o, 64);
    if ((tid & 63) == 0) red[tid >> 6] = s;
    __syncthreads();
    s = red[0] + red[1] + red[2] + red[3];
    float inv = 1.f / s;
    for (int j = tid; j < LL; j += 256) p[j] = buf[j] * inv;
}

// ---------------------------------------------------------------------------
// rel_attn gather + rel_attn @ aV accumulated into ctx.
// rel[0] = sum_{j<=i-64} attn, rel[128] = sum_{j>=i+64} attn,
// rel[r] = attn[i + r - 64] for r in [1,127] (0 if out of range).
// ---------------------------------------------------------------------------
__global__ __launch_bounds__(256) void relctx_kernel(const float* __restrict__ attn,
                                                     const float* __restrict__ aV,
                                                     float* __restrict__ ctx) {
    __shared__ float rel[RR];
    __shared__ float red[4];
    const int row = blockIdx.x;
    const int i = row & (LL - 1);
    const float* arow = attn + (size_t)row * LL;
    const int tid = threadIdx.x;

    float s = 0.f;
    for (int j = tid; j <= i - KREL; j += 256) s += arow[j];
#pragma unroll
    for (int o = 32; o; o >>= 1) s += __shfl_down(s, o, 64);
    if ((tid & 63) == 0) red[tid >> 6] = s;
    __syncthreads();
    if (tid == 0) rel[0] = red[0] + red[1] + red[2] + red[3];
    __syncthreads();

    float s2 = 0.f;
    for (int j = i + KREL + tid; j < LL; j += 256) s2 += arow[j];
#pragma unroll
    for (int o = 32; o; o >>= 1) s2 += __shfl_down(s2, o, 64);
    if ((tid & 63) == 0) red[tid >> 6] = s2;
    __syncthreads();
    if (tid == 0) rel[128] = red[0] + red[1] + red[2] + red[3];
    if (tid >= 1 && tid <= 127) {
        int j = i + tid - KREL;
        rel[tid] = (j >= 0 && j < LL) ? arow[j] : 0.f;
    }
    __syncthreads();

    for (int d = tid; d < DMIN; d += 256) {
        float acc = 0.f;
#pragma unroll 4
        for (int r = 0; r < RR; ++r) acc += rel[r] * aV[r * DMIN + d];
        ctx[(size_t)row * DMIN + d] += acc;
    }
}

// ---------------------------------------------------------------------------
// In-place LayerNorm over rows of 512 (two-pass mean/var like the reference).
// ---------------------------------------------------------------------------
__global__ __launch_bounds__(256) void layernorm_kernel(float* __restrict__ Y,
                                                        const float* __restrict__ gamma,
                                                        const float* __restrict__ beta) {
    __shared__ float red[4];
    const int row = blockIdx.x;
    float* p = Y + (size_t)row * DMIN;
    const int tid = threadIdx.x;
    float x0 = p[tid], x1 = p[tid + 256];
    float s = x0 + x1;
#pragma unroll
    for (int o = 32; o; o >>= 1) s += __shfl_down(s, o, 64);
    if ((tid & 63) == 0) red[tid >> 6] = s;
    __syncthreads();
    float mu = (red[0] + red[1] + red[2] + red[3]) * (1.f / 512.f);
    __syncthreads();
    float d0 = x0 - mu, d1 = x1 - mu;
    float v = d0 * d0 + d1 * d1;
#pragma unroll
    for (int o = 32; o; o >>= 1) v += __shfl_down(v, o, 64);
    if ((tid & 63) == 0) red[tid >> 6] = v;
    __syncthreads();
    float var = (red[0] + red[1] + red[2] + red[3]) * (1.f / 512.f);
    float inv = rsqrtf(var + 1e-5f);
    p[tid] = d0 * inv * gamma[tid] + beta[tid];
    p[tid + 256] = d1 * inv * gamma[tid + 256] + beta[tid + 256];
}

// ---------------------------------------------------------------------------
extern "C" void kernel_launch(void* const* d_in, const int* in_sizes, int n_in,
                              void* d_out, int out_size, void* d_ws, size_t ws_size,
                              hipStream_t stream) {
    const float* Xmaj  = (const float*)d_in[0];
    const float* Xmin  = (const float*)d_in[1];
    const float* Wq    = (const float*)d_in[2];
    const float* Wk    = (const float*)d_in[3];
    const float* Wv    = (const float*)d_in[4];
    const float* aK    = (const float*)d_in[5];
    const float* aV    = (const float*)d_in[6];
    const float* gamma = (const float*)d_in[7];
    const float* beta  = (const float*)d_in[8];

    float* Y    = (float*)d_out;                       // [8*2048, 512]
    float* attn = Y + (size_t)NB * LL * DMIN;          // [8*2048, 2048]

    float* ws   = (float*)d_ws;
    float* q    = ws;                                  // [16384, 512]
    float* kbuf = q    + (size_t)NB * LL * DMIN;       // [16384, 512]
    float* vbuf = kbuf + (size_t)NB * LL * DMIN;       // [16384, 512]
    float* relS = vbuf + (size_t)NB * LL * DMIN;       // [16384, 129]

    const int M = NB * LL;  // 16384
    dim3 blk(256);

    // q = X_major @ Wq  (M x 1024 @ 1024 x 512)
    gemm_nn<<<dim3(DMIN / 64, M / 64, 1), blk, 0, stream>>>(Xmaj, Wq, q, M, DMIN, DMAJ, 0, 0, 0);
    // k = X_minor @ Wk  (M x 512 @ 512 x 512)
    gemm_nn<<<dim3(DMIN / 64, M / 64, 1), blk, 0, stream>>>(Xmin, Wk, kbuf, M, DMIN, DMIN, 0, 0, 0);
    // v = X_minor @ Wv
    gemm_nn<<<dim3(DMIN / 64, M / 64, 1), blk, 0, stream>>>(Xmin, Wv, vbuf, M, DMIN, DMIN, 0, 0, 0);
    // rel_scores = q @ aK^T  (M x 512 @ (129 x 512)^T)
    gemm_nt_bounds<<<dim3((RR + 63) / 64, M / 64, 1), blk, 0, stream>>>(q, aK, relS, M, RR, DMIN);
    // scores (+bias, scale) -> attn region
    scores_kernel<<<dim3(LL / 64, LL / 64, NB), blk, 0, stream>>>(q, kbuf, relS, attn);
    // softmax in place
    softmax_kernel<<<dim3(M), blk, 0, stream>>>(attn);
    // ctx = attn @ v -> Y region
    gemm_nn<<<dim3(DMIN / 64, LL / 64, NB), blk, 0, stream>>>(
        attn, vbuf, Y, LL, DMIN, LL,
        (size_t)LL * LL, (size_t)LL * DMIN, (size_t)LL * DMIN);
    // ctx += rel_attn @ aV
    relctx_kernel<<<dim3(M), blk, 0, stream>>>(attn, aV, Y);
    // LayerNorm in place
    layernorm_kernel<<<dim3(M), blk, 0, stream>>>(Y, gamma, beta);
}

// Round 5
// 977.142 us; speedup vs baseline: 2.5549x; 2.5549x over previous
//
#include <hip/hip_runtime.h>
#include <math.h>

#define NB   8
#define LL   2048
#define DMAJ 1024
#define DMIN 512
#define RR   129
#define KREL 64

typedef short s16x8 __attribute__((ext_vector_type(8)));
typedef float f32x4 __attribute__((ext_vector_type(4)));

__device__ __forceinline__ unsigned short f2bf(float f) {
    union { float f; unsigned u; } v; v.f = f;
    unsigned r = v.u + 0x7fffu + ((v.u >> 16) & 1u);
    return (unsigned short)(r >> 16);
}

__device__ __forceinline__ void gload_lds16(const void* g, void* l) {
    __builtin_amdgcn_global_load_lds(
        (const __attribute__((address_space(1))) void*)g,
        (__attribute__((address_space(3))) void*)l, 16, 0, 0);
}

// ---------------------------------------------------------------------------
// bf16 MFMA NT GEMM: C[M,N] = A[M,K] @ B[N,K]^T.
// A fp32 in global (reg-staged -> bf16 LDS), B bf16 in global (global_load_lds).
// 128x128 tile, BK=64, 256 threads (4 waves, 2x2), 16x16x32 MFMA.
// EPI: 0 = fp32 C, 1 = bf16 C, 2 = fp32 C with rel-pos bias + 1/sqrt(512).
// Batched via blockIdx.z with element strides sA/sB/sC (sC in C's dtype).
// ---------------------------------------------------------------------------
template<int EPI>
__global__ __launch_bounds__(256) void mfma_nt(
    const float* __restrict__ A, const unsigned short* __restrict__ B,
    void* __restrict__ Cv,
    int M, int N, int K, int lda, int ldb, int ldc,
    long sA, long sB, long sC,
    const float* __restrict__ relS, long sRel)
{
    __shared__ unsigned short Al[128 * 64];
    __shared__ unsigned short Bl[128 * 64];
    const int tid = threadIdx.x;
    const int lane = tid & 63;
    const int w  = tid >> 6;
    const int wm = w >> 1, wn = w & 1;
    const int fr = lane & 15;   // A-row / B-col within fragment
    const int kg = lane >> 4;   // k-group 0..3
    const int m0 = blockIdx.y * 128, n0 = blockIdx.x * 128;
    const int b = blockIdx.z;
    const float* Ab = A + (size_t)b * sA;
    const unsigned short* Bb = B + (size_t)b * sB;

    f32x4 acc[4][4];
#pragma unroll
    for (int i = 0; i < 4; ++i)
#pragma unroll
        for (int j = 0; j < 4; ++j) acc[i][j] = f32x4{0.f, 0.f, 0.f, 0.f};

    for (int k0 = 0; k0 < K; k0 += 64) {
        __syncthreads();
        // B tile [128 n][64 k] bf16 -> LDS, linear in thread order (4 passes)
#pragma unroll
        for (int p = 0; p < 4; ++p) {
            int idx = p * 256 + tid;
            int row = idx >> 3;
            int c8  = (idx & 7) * 8;
            gload_lds16(Bb + (size_t)(n0 + row) * ldb + k0 + c8, &Bl[idx * 8]);
        }
        // A tile [128 m][64 k]: fp32 load -> cvt bf16 -> ds_write_b128
#pragma unroll
        for (int p = 0; p < 4; ++p) {
            int idx = p * 256 + tid;
            int row = idx >> 3;
            int c8  = (idx & 7) * 8;
            const float* src = Ab + (size_t)(m0 + row) * lda + k0 + c8;
            float4 f0 = *(const float4*)src;
            float4 f1 = *(const float4*)(src + 4);
            union { unsigned short u[8]; int4 v; } pk;
            pk.u[0] = f2bf(f0.x); pk.u[1] = f2bf(f0.y);
            pk.u[2] = f2bf(f0.z); pk.u[3] = f2bf(f0.w);
            pk.u[4] = f2bf(f1.x); pk.u[5] = f2bf(f1.y);
            pk.u[6] = f2bf(f1.z); pk.u[7] = f2bf(f1.w);
            *(int4*)&Al[idx * 8] = pk.v;
        }
        __syncthreads();
#pragma unroll
        for (int kk = 0; kk < 2; ++kk) {
            s16x8 a[4], bf[4];
#pragma unroll
            for (int mi = 0; mi < 4; ++mi)
                a[mi] = *(const s16x8*)&Al[(wm * 64 + mi * 16 + fr) * 64 + kk * 32 + kg * 8];
#pragma unroll
            for (int ni = 0; ni < 4; ++ni)
                bf[ni] = *(const s16x8*)&Bl[(wn * 64 + ni * 16 + fr) * 64 + kk * 32 + kg * 8];
#pragma unroll
            for (int mi = 0; mi < 4; ++mi)
#pragma unroll
                for (int ni = 0; ni < 4; ++ni)
                    acc[mi][ni] = __builtin_amdgcn_mfma_f32_16x16x32_bf16(
                        a[mi], bf[ni], acc[mi][ni], 0, 0, 0);
        }
    }

    // Epilogue. D layout: col = lane&15, row = (lane>>4)*4 + reg.
    const float scale = 0.044194173824159216f;  // 1/sqrt(512)
#pragma unroll
    for (int mi = 0; mi < 4; ++mi) {
#pragma unroll
        for (int ni = 0; ni < 4; ++ni) {
            int n  = n0 + wn * 64 + ni * 16 + fr;
            int mb = m0 + wm * 64 + mi * 16 + kg * 4;
#pragma unroll
            for (int r = 0; r < 4; ++r) {
                int m = mb + r;
                float v = acc[mi][ni][r];
                if (EPI == 0) {
                    ((float*)Cv)[(size_t)b * sC + (size_t)m * ldc + n] = v;
                } else if (EPI == 1) {
                    ((unsigned short*)Cv)[(size_t)b * sC + (size_t)m * ldc + n] = f2bf(v);
                } else {
                    const float* rSb = relS + (size_t)b * sRel;
                    int rr = n - m;
                    rr = rr < -KREL ? -KREL : (rr > KREL ? KREL : rr);
                    float bias = rSb[(size_t)m * RR + (rr + KREL)];
                    ((float*)Cv)[(size_t)b * sC + (size_t)m * ldc + n] = (v + bias) * scale;
                }
            }
        }
    }
}

// ---------------------------------------------------------------------------
// Prep kernels: weight transpose/cast + X cast.
// ---------------------------------------------------------------------------
__global__ __launch_bounds__(256) void tcast_bf16_512(const float* __restrict__ W,
                                                      unsigned short* __restrict__ WT,
                                                      int R) {
    int i = blockIdx.x * 256 + threadIdx.x;   // over R*512, inner dim 512
    if (i >= R * 512) return;
    int r = i >> 9, c = i & 511;
    WT[(size_t)c * R + r] = f2bf(W[i]);
}

__global__ __launch_bounds__(256) void transpose_f32_512(const float* __restrict__ W,
                                                         float* __restrict__ WT) {
    int i = blockIdx.x * 256 + threadIdx.x;   // 512*512
    int r = i >> 9, c = i & 511;
    WT[(size_t)c * 512 + r] = W[i];
}

__global__ __launch_bounds__(256) void cast_bf16_vec(const float* __restrict__ X,
                                                     unsigned short* __restrict__ Xb,
                                                     long n8) {
    long i = (long)blockIdx.x * 256 + threadIdx.x;
    if (i >= n8) return;
    float4 f0 = ((const float4*)X)[2 * i];
    float4 f1 = ((const float4*)X)[2 * i + 1];
    union { unsigned short u[8]; int4 v; } pk;
    pk.u[0] = f2bf(f0.x); pk.u[1] = f2bf(f0.y);
    pk.u[2] = f2bf(f0.z); pk.u[3] = f2bf(f0.w);
    pk.u[4] = f2bf(f1.x); pk.u[5] = f2bf(f1.y);
    pk.u[6] = f2bf(f1.z); pk.u[7] = f2bf(f1.w);
    ((int4*)Xb)[i] = pk.v;
}

// ---------------------------------------------------------------------------
// fp32 NT GEMM with N-bounds (rel_scores: M=16384, N=129, K=512).
// ---------------------------------------------------------------------------
__global__ __launch_bounds__(256) void gemm_nt_bounds(const float* __restrict__ A,
                                                      const float* __restrict__ Bm,
                                                      float* __restrict__ C,
                                                      int M, int N, int K) {
    __shared__ float As[16][65];
    __shared__ float Bs[16][65];
    const int tid = threadIdx.x;
    const int tx = tid & 15, ty = tid >> 4;
    const int m0 = blockIdx.y * 64, n0 = blockIdx.x * 64;
    float c[4][4] = {};
    for (int k0 = 0; k0 < K; k0 += 16) {
        for (int idx = tid; idx < 1024; idx += 256) {
            int m = idx >> 4, k = idx & 15;
            As[k][m] = A[(size_t)(m0 + m) * K + k0 + k];
        }
        for (int idx = tid; idx < 1024; idx += 256) {
            int n = idx >> 4, k = idx & 15;
            int ng = n0 + n;
            Bs[k][n] = (ng < N) ? Bm[(size_t)ng * K + k0 + k] : 0.f;
        }
        __syncthreads();
#pragma unroll
        for (int k = 0; k < 16; ++k) {
            float a[4], b[4];
#pragma unroll
            for (int i = 0; i < 4; ++i) a[i] = As[k][ty * 4 + i];
#pragma unroll
            for (int j = 0; j < 4; ++j) b[j] = Bs[k][tx * 4 + j];
#pragma unroll
            for (int i = 0; i < 4; ++i)
#pragma unroll
                for (int j = 0; j < 4; ++j)
                    c[i][j] += a[i] * b[j];
        }
        __syncthreads();
    }
#pragma unroll
    for (int i = 0; i < 4; ++i)
#pragma unroll
        for (int j = 0; j < 4; ++j) {
            int ng = n0 + tx * 4 + j;
            if (ng < N) C[(size_t)(m0 + ty * 4 + i) * N + ng] = c[i][j];
        }
}

// ---------------------------------------------------------------------------
// In-place row softmax over rows of length 2048.
// ---------------------------------------------------------------------------
__global__ __launch_bounds__(256) void softmax_kernel(float* __restrict__ attn) {
    __shared__ float buf[LL];
    __shared__ float red[4];
    const size_t row = blockIdx.x;
    float* p = attn + row * LL;
    const int tid = threadIdx.x;
    float m = -1e30f;
    for (int j = tid; j < LL; j += 256) {
        float v = p[j];
        buf[j] = v;
        m = fmaxf(m, v);
    }
#pragma unroll
    for (int o = 32; o; o >>= 1) m = fmaxf(m, __shfl_down(m, o, 64));
    if ((tid & 63) == 0) red[tid >> 6] = m;
    __syncthreads();
    m = fmaxf(fmaxf(red[0], red[1]), fmaxf(red[2], red[3]));
    __syncthreads();
    float s = 0.f;
    for (int j = tid; j < LL; j += 256) {
        float e = __expf(buf[j] - m);
        buf[j] = e;
        s += e;
    }
#pragma unroll
    for (int o = 32; o; o >>= 1) s += __shfl_down(s, o, 64);
    if ((tid & 63) == 0) red[tid >> 6] = s;
    __syncthreads();
    s = red[0] + red[1] + red[2] + red[3];
    float inv = 1.f / s;
    for (int j = tid; j < LL; j += 256) p[j] = buf[j] * inv;
}

// ---------------------------------------------------------------------------
// rel_attn gather + rel_attn @ aV accumulated into ctx.
// ---------------------------------------------------------------------------
__global__ __launch_bounds__(256) void relctx_kernel(const float* __restrict__ attn,
                                                     const float* __restrict__ aV,
                                                     float* __restrict__ ctx) {
    __shared__ float rel[RR];
    __shared__ float red[4];
    const int row = blockIdx.x;
    const int i = row & (LL - 1);
    const float* arow = attn + (size_t)row * LL;
    const int tid = threadIdx.x;

    float s = 0.f;
    for (int j = tid; j <= i - KREL; j += 256) s += arow[j];
#pragma unroll
    for (int o = 32; o; o >>= 1) s += __shfl_down(s, o, 64);
    if ((tid & 63) == 0) red[tid >> 6] = s;
    __syncthreads();
    if (tid == 0) rel[0] = red[0] + red[1] + red[2] + red[3];
    __syncthreads();

    float s2 = 0.f;
    for (int j = i + KREL + tid; j < LL; j += 256) s2 += arow[j];
#pragma unroll
    for (int o = 32; o; o >>= 1) s2 += __shfl_down(s2, o, 64);
    if ((tid & 63) == 0) red[tid >> 6] = s2;
    __syncthreads();
    if (tid == 0) rel[128] = red[0] + red[1] + red[2] + red[3];
    if (tid >= 1 && tid <= 127) {
        int j = i + tid - KREL;
        rel[tid] = (j >= 0 && j < LL) ? arow[j] : 0.f;
    }
    __syncthreads();

    for (int d = tid; d < DMIN; d += 256) {
        float acc = 0.f;
#pragma unroll 4
        for (int r = 0; r < RR; ++r) acc += rel[r] * aV[r * DMIN + d];
        ctx[(size_t)row * DMIN + d] += acc;
    }
}

// ---------------------------------------------------------------------------
// In-place LayerNorm over rows of 512.
// ---------------------------------------------------------------------------
__global__ __launch_bounds__(256) void layernorm_kernel(float* __restrict__ Y,
                                                        const float* __restrict__ gamma,
                                                        const float* __restrict__ beta) {
    __shared__ float red[4];
    const int row = blockIdx.x;
    float* p = Y + (size_t)row * DMIN;
    const int tid = threadIdx.x;
    float x0 = p[tid], x1 = p[tid + 256];
    float s = x0 + x1;
#pragma unroll
    for (int o = 32; o; o >>= 1) s += __shfl_down(s, o, 64);
    if ((tid & 63) == 0) red[tid >> 6] = s;
    __syncthreads();
    float mu = (red[0] + red[1] + red[2] + red[3]) * (1.f / 512.f);
    __syncthreads();
    float d0 = x0 - mu, d1 = x1 - mu;
    float v = d0 * d0 + d1 * d1;
#pragma unroll
    for (int o = 32; o; o >>= 1) v += __shfl_down(v, o, 64);
    if ((tid & 63) == 0) red[tid >> 6] = v;
    __syncthreads();
    float var = (red[0] + red[1] + red[2] + red[3]) * (1.f / 512.f);
    float inv = rsqrtf(var + 1e-5f);
    p[tid] = d0 * inv * gamma[tid] + beta[tid];
    p[tid + 256] = d1 * inv * gamma[tid + 256] + beta[tid + 256];
}

// ---------------------------------------------------------------------------
extern "C" void kernel_launch(void* const* d_in, const int* in_sizes, int n_in,
                              void* d_out, int out_size, void* d_ws, size_t ws_size,
                              hipStream_t stream) {
    const float* Xmaj  = (const float*)d_in[0];
    const float* Xmin  = (const float*)d_in[1];
    const float* Wq    = (const float*)d_in[2];
    const float* Wk    = (const float*)d_in[3];
    const float* Wv    = (const float*)d_in[4];
    const float* aK    = (const float*)d_in[5];
    const float* aV    = (const float*)d_in[6];
    const float* gamma = (const float*)d_in[7];
    const float* beta  = (const float*)d_in[8];

    float* Y    = (float*)d_out;                       // [16384, 512] fp32
    float* attn = Y + (size_t)NB * LL * DMIN;          // [8, 2048, 2048] fp32

    // Workspace layout (~95 MB)
    float* q       = (float*)d_ws;                     // [16384, 512] fp32
    float* relSbuf = q + (size_t)16384 * 512;          // [16384, 129] fp32
    float* WvT     = relSbuf + (size_t)16384 * RR;     // [512, 512] fp32
    unsigned short* k_bf    = (unsigned short*)(WvT + 512 * 512);  // [16384, 512]
    unsigned short* vT_bf   = k_bf + (size_t)16384 * 512;          // [512, 16384] (= v^T per batch cols)
    unsigned short* Xmin_bf = vT_bf + (size_t)512 * 16384;         // [16384, 512]
    unsigned short* WqT_bf  = Xmin_bf + (size_t)16384 * 512;       // [512, 1024]
    unsigned short* WkT_bf  = WqT_bf + (size_t)512 * 1024;         // [512, 512]

    const int M = NB * LL;  // 16384
    dim3 blk(256);

    // --- prep: weight transposes + X_minor cast ---
    tcast_bf16_512<<<dim3(2048), blk, 0, stream>>>(Wq, WqT_bf, 1024);
    tcast_bf16_512<<<dim3(1024), blk, 0, stream>>>(Wk, WkT_bf, 512);
    transpose_f32_512<<<dim3(1024), blk, 0, stream>>>(Wv, WvT);
    cast_bf16_vec<<<dim3(4096), blk, 0, stream>>>(Xmin, Xmin_bf, (long)M * DMIN / 8);

    // --- projections (MFMA) ---
    // q = X_major @ Wq  -> fp32 (needed for rel_scores)
    mfma_nt<0><<<dim3(4, 128, 1), blk, 0, stream>>>(
        Xmaj, WqT_bf, q, M, DMIN, DMAJ, DMAJ, DMAJ, DMIN, 0, 0, 0, nullptr, 0);
    // k = X_minor @ Wk -> bf16
    mfma_nt<1><<<dim3(4, 128, 1), blk, 0, stream>>>(
        Xmin, WkT_bf, k_bf, M, DMIN, DMIN, DMIN, DMIN, DMIN, 0, 0, 0, nullptr, 0);
    // vT[d][b*2048+m] = (X_minor @ Wv)[m][d] -> bf16, computed as WvT @ Xmin^T
    mfma_nt<1><<<dim3(128, 4, 1), blk, 0, stream>>>(
        WvT, Xmin_bf, vT_bf, DMIN, M, DMIN, DMIN, DMIN, M, 0, 0, 0, nullptr, 0);

    // rel_scores = q @ aK^T (fp32, small)
    gemm_nt_bounds<<<dim3(3, 256, 1), blk, 0, stream>>>(q, aK, relSbuf, M, RR, DMIN);

    // scores (+rel bias, scale) -> attn
    mfma_nt<2><<<dim3(16, 16, NB), blk, 0, stream>>>(
        q, k_bf, attn, LL, LL, DMIN, DMIN, DMIN, LL,
        (long)LL * DMIN, (long)LL * DMIN, (long)LL * LL, relSbuf, (long)LL * RR);

    // softmax in place
    softmax_kernel<<<dim3(M), blk, 0, stream>>>(attn);

    // ctx = attn @ v -> Y  (NT against vT)
    mfma_nt<0><<<dim3(4, 16, NB), blk, 0, stream>>>(
        attn, vT_bf, Y, LL, DMIN, LL, LL, M, DMIN,
        (long)LL * LL, (long)LL, (long)LL * DMIN, nullptr, 0);

    // ctx += rel_attn @ aV
    relctx_kernel<<<dim3(M), blk, 0, stream>>>(attn, aV, Y);
    // LayerNorm in place
    layernorm_kernel<<<dim3(M), blk, 0, stream>>>(Y, gamma, beta);
}

// Round 7
// 671.232 us; speedup vs baseline: 3.7192x; 1.4557x over previous
//
#include <hip/hip_runtime.h>
#include <math.h>

#define NB   8
#define LL   2048
#define DMAJ 1024
#define DMIN 512
#define RR   129
#define KREL 64

typedef short s16x8 __attribute__((ext_vector_type(8)));
typedef float f32x4 __attribute__((ext_vector_type(4)));

__device__ __forceinline__ unsigned short f2bf(float f) {
    union { float f; unsigned u; } v; v.f = f;
    unsigned r = v.u + 0x7fffu + ((v.u >> 16) & 1u);
    return (unsigned short)(r >> 16);
}

__device__ __forceinline__ float bf2f(unsigned short b) {
    union { unsigned u; float f; } v; v.u = (unsigned)b << 16;
    return v.f;
}

__device__ __forceinline__ void gload_lds16(const void* g, void* l) {
    __builtin_amdgcn_global_load_lds(
        (const __attribute__((address_space(1))) void*)g,
        (__attribute__((address_space(3))) void*)l, 16, 0, 0);
}

// ---------------------------------------------------------------------------
// bf16 MFMA NT GEMM: C[M,N] = A[M,K] @ B[N,K]^T.
// A fp32 in global (reg-staged -> bf16 LDS), B bf16 in global (global_load_lds).
// 128x128 tile, BK=64, 256 threads (4 waves, 2x2), 16x16x32 MFMA.
// EPI: 0 = fp32 C, 1 = bf16 C, 2 = fp32 C with rel-pos bias (bf16, stride 256)
//      + 1/sqrt(512) scale.
// Batched via blockIdx.z with element strides sA/sB/sC (sC in C's dtype).
// ---------------------------------------------------------------------------
template<int EPI>
__global__ __launch_bounds__(256) void mfma_nt(
    const float* __restrict__ A, const unsigned short* __restrict__ B,
    void* __restrict__ Cv,
    int M, int N, int K, int lda, int ldb, int ldc,
    long sA, long sB, long sC,
    const float* __restrict__ relS, long sRel)
{
    __shared__ unsigned short Al[128 * 64];
    __shared__ unsigned short Bl[128 * 64];
    const int tid = threadIdx.x;
    const int lane = tid & 63;
    const int w  = tid >> 6;
    const int wm = w >> 1, wn = w & 1;
    const int fr = lane & 15;   // A-row / B-col within fragment
    const int kg = lane >> 4;   // k-group 0..3
    const int m0 = blockIdx.y * 128, n0 = blockIdx.x * 128;
    const int b = blockIdx.z;
    const float* Ab = A + (size_t)b * sA;
    const unsigned short* Bb = B + (size_t)b * sB;

    f32x4 acc[4][4];
#pragma unroll
    for (int i = 0; i < 4; ++i)
#pragma unroll
        for (int j = 0; j < 4; ++j) acc[i][j] = f32x4{0.f, 0.f, 0.f, 0.f};

    for (int k0 = 0; k0 < K; k0 += 64) {
        __syncthreads();
        // B tile [128 n][64 k] bf16 -> LDS, linear in thread order (4 passes)
#pragma unroll
        for (int p = 0; p < 4; ++p) {
            int idx = p * 256 + tid;
            int row = idx >> 3;
            int c8  = (idx & 7) * 8;
            gload_lds16(Bb + (size_t)(n0 + row) * ldb + k0 + c8, &Bl[idx * 8]);
        }
        // A tile [128 m][64 k]: fp32 load -> cvt bf16 -> ds_write_b128
#pragma unroll
        for (int p = 0; p < 4; ++p) {
            int idx = p * 256 + tid;
            int row = idx >> 3;
            int c8  = (idx & 7) * 8;
            const float* src = Ab + (size_t)(m0 + row) * lda + k0 + c8;
            float4 f0 = *(const float4*)src;
            float4 f1 = *(const float4*)(src + 4);
            union { unsigned short u[8]; int4 v; } pk;
            pk.u[0] = f2bf(f0.x); pk.u[1] = f2bf(f0.y);
            pk.u[2] = f2bf(f0.z); pk.u[3] = f2bf(f0.w);
            pk.u[4] = f2bf(f1.x); pk.u[5] = f2bf(f1.y);
            pk.u[6] = f2bf(f1.z); pk.u[7] = f2bf(f1.w);
            *(int4*)&Al[idx * 8] = pk.v;
        }
        __syncthreads();
#pragma unroll
        for (int kk = 0; kk < 2; ++kk) {
            s16x8 a[4], bf[4];
#pragma unroll
            for (int mi = 0; mi < 4; ++mi)
                a[mi] = *(const s16x8*)&Al[(wm * 64 + mi * 16 + fr) * 64 + kk * 32 + kg * 8];
#pragma unroll
            for (int ni = 0; ni < 4; ++ni)
                bf[ni] = *(const s16x8*)&Bl[(wn * 64 + ni * 16 + fr) * 64 + kk * 32 + kg * 8];
#pragma unroll
            for (int mi = 0; mi < 4; ++mi)
#pragma unroll
                for (int ni = 0; ni < 4; ++ni)
                    acc[mi][ni] = __builtin_amdgcn_mfma_f32_16x16x32_bf16(
                        a[mi], bf[ni], acc[mi][ni], 0, 0, 0);
        }
    }

    // Epilogue. D layout: col = lane&15, row = (lane>>4)*4 + reg.
    const float scale = 0.044194173824159216f;  // 1/sqrt(512)
#pragma unroll
    for (int mi = 0; mi < 4; ++mi) {
#pragma unroll
        for (int ni = 0; ni < 4; ++ni) {
            int n  = n0 + wn * 64 + ni * 16 + fr;
            int mb = m0 + wm * 64 + mi * 16 + kg * 4;
#pragma unroll
            for (int r = 0; r < 4; ++r) {
                int m = mb + r;
                float v = acc[mi][ni][r];
                if (EPI == 0) {
                    ((float*)Cv)[(size_t)b * sC + (size_t)m * ldc + n] = v;
                } else if (EPI == 1) {
                    ((unsigned short*)Cv)[(size_t)b * sC + (size_t)m * ldc + n] = f2bf(v);
                } else {
                    const unsigned short* rSb = (const unsigned short*)relS + (size_t)b * sRel;
                    int rr = n - m;
                    rr = rr < -KREL ? -KREL : (rr > KREL ? KREL : rr);
                    float bias = bf2f(rSb[(size_t)m * 256 + (rr + KREL)]);
                    ((float*)Cv)[(size_t)b * sC + (size_t)m * ldc + n] = (v + bias) * scale;
                }
            }
        }
    }
}

// ---------------------------------------------------------------------------
// Prep kernels: weight transpose/cast + X cast + aK pad-cast.
// ---------------------------------------------------------------------------
__global__ __launch_bounds__(256) void tcast_bf16_512(const float* __restrict__ W,
                                                      unsigned short* __restrict__ WT,
                                                      int R) {
    int i = blockIdx.x * 256 + threadIdx.x;   // over R*512, inner dim 512
    if (i >= R * 512) return;
    int r = i >> 9, c = i & 511;
    WT[(size_t)c * R + r] = f2bf(W[i]);
}

__global__ __launch_bounds__(256) void transpose_f32_512(const float* __restrict__ W,
                                                         float* __restrict__ WT) {
    int i = blockIdx.x * 256 + threadIdx.x;   // 512*512
    int r = i >> 9, c = i & 511;
    WT[(size_t)c * 512 + r] = W[i];
}

__global__ __launch_bounds__(256) void cast_bf16_vec(const float* __restrict__ X,
                                                     unsigned short* __restrict__ Xb,
                                                     long n8) {
    long i = (long)blockIdx.x * 256 + threadIdx.x;
    if (i >= n8) return;
    float4 f0 = ((const float4*)X)[2 * i];
    float4 f1 = ((const float4*)X)[2 * i + 1];
    union { unsigned short u[8]; int4 v; } pk;
    pk.u[0] = f2bf(f0.x); pk.u[1] = f2bf(f0.y);
    pk.u[2] = f2bf(f0.z); pk.u[3] = f2bf(f0.w);
    pk.u[4] = f2bf(f1.x); pk.u[5] = f2bf(f1.y);
    pk.u[6] = f2bf(f1.z); pk.u[7] = f2bf(f1.w);
    ((int4*)Xb)[i] = pk.v;
}

// aK [129][512] fp32 -> [256][512] bf16, rows 129..255 zeroed.
__global__ __launch_bounds__(256) void pad_aK_kernel(const float* __restrict__ aK,
                                                     unsigned short* __restrict__ out) {
    int i = blockIdx.x * 256 + threadIdx.x;   // 256*512 = 131072
    int r = i >> 9;
    out[i] = (r < RR) ? f2bf(aK[i]) : (unsigned short)0;
}

// ---------------------------------------------------------------------------
// In-place row softmax over rows of length 2048 (float4 vectorized).
// ---------------------------------------------------------------------------
__global__ __launch_bounds__(256) void softmax_kernel(float* __restrict__ attn) {
    __shared__ float buf[LL];
    __shared__ float red[4];
    float* p = attn + (size_t)blockIdx.x * LL;
    const int tid = threadIdx.x;
    float m = -1e30f;
#pragma unroll
    for (int t = 0; t < 2; ++t) {
        int j4 = tid + t * 256;
        float4 v = ((const float4*)p)[j4];
        ((float4*)buf)[j4] = v;
        m = fmaxf(m, fmaxf(fmaxf(v.x, v.y), fmaxf(v.z, v.w)));
    }
#pragma unroll
    for (int o = 32; o; o >>= 1) m = fmaxf(m, __shfl_down(m, o, 64));
    if ((tid & 63) == 0) red[tid >> 6] = m;
    __syncthreads();
    m = fmaxf(fmaxf(red[0], red[1]), fmaxf(red[2], red[3]));
    __syncthreads();
    float s = 0.f;
#pragma unroll
    for (int t = 0; t < 2; ++t) {
        int j4 = tid + t * 256;
        float4 v = ((const float4*)buf)[j4];
        v.x = __expf(v.x - m); v.y = __expf(v.y - m);
        v.z = __expf(v.z - m); v.w = __expf(v.w - m);
        ((float4*)buf)[j4] = v;
        s += v.x + v.y + v.z + v.w;
    }
#pragma unroll
    for (int o = 32; o; o >>= 1) s += __shfl_down(s, o, 64);
    if ((tid & 63) == 0) red[tid >> 6] = s;
    __syncthreads();
    s = red[0] + red[1] + red[2] + red[3];
    float inv = 1.f / s;
#pragma unroll
    for (int t = 0; t < 2; ++t) {
        int j4 = tid + t * 256;
        float4 v = ((const float4*)buf)[j4];
        v.x *= inv; v.y *= inv; v.z *= inv; v.w *= inv;
        ((float4*)p)[j4] = v;
    }
}

// ---------------------------------------------------------------------------
// rel_attn gather + rel_attn @ aV accumulated into ctx. 16 rows per block:
// phase 1: 16-thread groups build rel[16][129] in LDS (single float4 pass
//          with masks + interior gather); phase 2: each thread owns
//          4 rows x 8 d-cols so one aV float4-pair feeds 32 FMAs.
// ---------------------------------------------------------------------------
#define BR 16
__global__ __launch_bounds__(256) void relctx_kernel(const float* __restrict__ attn,
                                                     const float* __restrict__ aV,
                                                     float* __restrict__ ctx) {
    __shared__ float rel[BR][132];
    const int tid = threadIdx.x;
    const int row0 = blockIdx.x * BR;
    const int g  = tid >> 4;        // group -> row row0+g
    const int lt = tid & 15;        // lane within group
    {
        const int row = row0 + g;
        const int i = row & (LL - 1);
        const float* arow = attn + (size_t)row * LL;
        float slow = 0.f, shigh = 0.f;
        const int lo = i - KREL, hi = i + KREL;
#pragma unroll 4
        for (int k = 0; k < 32; ++k) {
            int j4 = lt + k * 16;
            float4 v = ((const float4*)arow)[j4];
            int j = j4 * 4;
            slow  += (j     <= lo ? v.x : 0.f) + (j + 1 <= lo ? v.y : 0.f)
                   + (j + 2 <= lo ? v.z : 0.f) + (j + 3 <= lo ? v.w : 0.f);
            shigh += (j     >= hi ? v.x : 0.f) + (j + 1 >= hi ? v.y : 0.f)
                   + (j + 2 >= hi ? v.z : 0.f) + (j + 3 >= hi ? v.w : 0.f);
        }
#pragma unroll
        for (int o = 1; o < 16; o <<= 1) {
            slow  += __shfl_xor(slow, o, 16);
            shigh += __shfl_xor(shigh, o, 16);
        }
        if (lt == 0) { rel[g][0] = slow; rel[g][128] = shigh; }
        for (int r = 1 + lt; r < 128; r += 16) {
            int j = i + r - KREL;
            rel[g][r] = (j >= 0 && j < LL) ? arow[j] : 0.f;
        }
    }
    __syncthreads();

    // phase 2: rows rw0..rw0+3, cols d0..d0+7
    const int rw0 = (tid >> 6) * 4;
    const int d0 = (tid & 63) * 8;
    float acc[4][8];
#pragma unroll
    for (int a = 0; a < 4; ++a)
#pragma unroll
        for (int d = 0; d < 8; ++d) acc[a][d] = 0.f;

    for (int r = 0; r < RR; ++r) {
        float4 av0 = *(const float4*)&aV[(size_t)r * DMIN + d0];
        float4 av1 = *(const float4*)&aV[(size_t)r * DMIN + d0 + 4];
        float rl[4];
#pragma unroll
        for (int a = 0; a < 4; ++a) rl[a] = rel[rw0 + a][r];
#pragma unroll
        for (int a = 0; a < 4; ++a) {
            acc[a][0] += rl[a] * av0.x; acc[a][1] += rl[a] * av0.y;
            acc[a][2] += rl[a] * av0.z; acc[a][3] += rl[a] * av0.w;
            acc[a][4] += rl[a] * av1.x; acc[a][5] += rl[a] * av1.y;
            acc[a][6] += rl[a] * av1.z; acc[a][7] += rl[a] * av1.w;
        }
    }
#pragma unroll
    for (int a = 0; a < 4; ++a) {
        float* dst = ctx + (size_t)(row0 + rw0 + a) * DMIN + d0;
        float4 c0 = *(float4*)dst;
        float4 c1 = *(float4*)(dst + 4);
        c0.x += acc[a][0]; c0.y += acc[a][1]; c0.z += acc[a][2]; c0.w += acc[a][3];
        c1.x += acc[a][4]; c1.y += acc[a][5]; c1.z += acc[a][6]; c1.w += acc[a][7];
        *(float4*)dst = c0;
        *(float4*)(dst + 4) = c1;
    }
}

// ---------------------------------------------------------------------------
// In-place LayerNorm over rows of 512.
// ---------------------------------------------------------------------------
__global__ __launch_bounds__(256) void layernorm_kernel(float* __restrict__ Y,
                                                        const float* __restrict__ gamma,
                                                        const float* __restrict__ beta) {
    __shared__ float red[4];
    const int row = blockIdx.x;
    float* p = Y + (size_t)row * DMIN;
    const int tid = threadIdx.x;
    float x0 = p[tid], x1 = p[tid + 256];
    float s = x0 + x1;
#pragma unroll
    for (int o = 32; o; o >>= 1) s += __shfl_down(s, o, 64);
    if ((tid & 63) == 0) red[tid >> 6] = s;
    __syncthreads();
    float mu = (red[0] + red[1] + red[2] + red[3]) * (1.f / 512.f);
    __syncthreads();
    float d0 = x0 - mu, d1 = x1 - mu;
    float v = d0 * d0 + d1 * d1;
#pragma unroll
    for (int o = 32; o; o >>= 1) v += __shfl_down(v, o, 64);
    if ((tid & 63) == 0) red[tid >> 6] = v;
    __syncthreads();
    float var = (red[0] + red[1] + red[2] + red[3]) * (1.f / 512.f);
    float inv = rsqrtf(var + 1e-5f);
    p[tid] = d0 * inv * gamma[tid] + beta[tid];
    p[tid + 256] = d1 * inv * gamma[tid + 256] + beta[tid + 256];
}

// ---------------------------------------------------------------------------
extern "C" void kernel_launch(void* const* d_in, const int* in_sizes, int n_in,
                              void* d_out, int out_size, void* d_ws, size_t ws_size,
                              hipStream_t stream) {
    const float* Xmaj  = (const float*)d_in[0];
    const float* Xmin  = (const float*)d_in[1];
    const float* Wq    = (const float*)d_in[2];
    const float* Wk    = (const float*)d_in[3];
    const float* Wv    = (const float*)d_in[4];
    const float* aK    = (const float*)d_in[5];
    const float* aV    = (const float*)d_in[6];
    const float* gamma = (const float*)d_in[7];
    const float* beta  = (const float*)d_in[8];

    float* Y    = (float*)d_out;                       // [16384, 512] fp32
    float* attn = Y + (size_t)NB * LL * DMIN;          // [8, 2048, 2048] fp32

    // Workspace layout (~95 MB)
    float* q = (float*)d_ws;                                        // [16384,512] f32
    unsigned short* relS_bf = (unsigned short*)(q + (size_t)16384 * 512);  // [16384,256] bf16
    float* WvT = (float*)(relS_bf + (size_t)16384 * 256);           // [512,512] f32
    unsigned short* k_bf    = (unsigned short*)(WvT + 512 * 512);   // [16384,512]
    unsigned short* vT_bf   = k_bf + (size_t)16384 * 512;           // [512,16384]
    unsigned short* Xmin_bf = vT_bf + (size_t)512 * 16384;          // [16384,512]
    unsigned short* WqT_bf  = Xmin_bf + (size_t)16384 * 512;        // [512,1024]
    unsigned short* WkT_bf  = WqT_bf + (size_t)512 * 1024;          // [512,512]
    unsigned short* aK_bf   = WkT_bf + (size_t)512 * 512;           // [256,512]

    const int M = NB * LL;  // 16384
    dim3 blk(256);

    // --- prep ---
    tcast_bf16_512<<<dim3(2048), blk, 0, stream>>>(Wq, WqT_bf, 1024);
    tcast_bf16_512<<<dim3(1024), blk, 0, stream>>>(Wk, WkT_bf, 512);
    transpose_f32_512<<<dim3(1024), blk, 0, stream>>>(Wv, WvT);
    cast_bf16_vec<<<dim3(4096), blk, 0, stream>>>(Xmin, Xmin_bf, (long)M * DMIN / 8);
    pad_aK_kernel<<<dim3(512), blk, 0, stream>>>(aK, aK_bf);

    // --- projections (MFMA) ---
    mfma_nt<0><<<dim3(4, 128, 1), blk, 0, stream>>>(
        Xmaj, WqT_bf, q, M, DMIN, DMAJ, DMAJ, DMAJ, DMIN, 0, 0, 0, nullptr, 0);
    mfma_nt<1><<<dim3(4, 128, 1), blk, 0, stream>>>(
        Xmin, WkT_bf, k_bf, M, DMIN, DMIN, DMIN, DMIN, DMIN, 0, 0, 0, nullptr, 0);
    mfma_nt<1><<<dim3(128, 4, 1), blk, 0, stream>>>(
        WvT, Xmin_bf, vT_bf, DMIN, M, DMIN, DMIN, DMIN, M, 0, 0, 0, nullptr, 0);

    // rel_scores = q @ aK^T -> bf16 [16384,256] (cols >=129 are exactly 0)
    mfma_nt<1><<<dim3(2, 128, 1), blk, 0, stream>>>(
        q, aK_bf, relS_bf, M, 256, DMIN, DMIN, DMIN, 256, 0, 0, 0, nullptr, 0);

    // scores (+rel bias, scale) -> attn
    mfma_nt<2><<<dim3(16, 16, NB), blk, 0, stream>>>(
        q, k_bf, attn, LL, LL, DMIN, DMIN, DMIN, LL,
        (long)LL * DMIN, (long)LL * DMIN, (long)LL * LL,
        (const float*)relS_bf, (long)LL * 256);

    // softmax in place
    softmax_kernel<<<dim3(M), blk, 0, stream>>>(attn);

    // ctx = attn @ v -> Y  (NT against vT)
    mfma_nt<0><<<dim3(4, 16, NB), blk, 0, stream>>>(
        attn, vT_bf, Y, LL, DMIN, LL, LL, M, DMIN,
        (long)LL * LL, (long)LL, (long)LL * DMIN, nullptr, 0);

    // ctx += rel_attn @ aV
    relctx_kernel<<<dim3(M / BR), blk, 0, stream>>>(attn, aV, Y);
    // LayerNorm in place
    layernorm_kernel<<<dim3(M), blk, 0, stream>>>(Y, gamma, beta);
}

// Round 17
// 668.456 us; speedup vs baseline: 3.7347x; 1.0042x over previous
//
#include <hip/hip_runtime.h>
#include <math.h>

#define NB   8
#define LL   2048
#define DMAJ 1024
#define DMIN 512
#define RR   129
#define KREL 64

typedef short s16x8 __attribute__((ext_vector_type(8)));
typedef float f32x4 __attribute__((ext_vector_type(4)));

__device__ __forceinline__ unsigned short f2bf(float f) {
    union { float f; unsigned u; } v; v.f = f;
    unsigned r = v.u + 0x7fffu + ((v.u >> 16) & 1u);
    return (unsigned short)(r >> 16);
}

__device__ __forceinline__ float bf2f(unsigned short b) {
    union { unsigned u; float f; } v; v.u = (unsigned)b << 16;
    return v.f;
}

__device__ __forceinline__ void gload_lds16(const void* g, void* l) {
    __builtin_amdgcn_global_load_lds(
        (const __attribute__((address_space(1))) void*)g,
        (__attribute__((address_space(3))) void*)l, 16, 0, 0);
}

// ---------------------------------------------------------------------------
// bf16 MFMA NT GEMM: C[M,N] = A[M,K] @ B[N,K]^T.  (projections / scores)
// 128x128 tile, BK=64, 256 threads (4 waves, 2x2), 16x16x32 MFMA.
// EPI: 0 = fp32 C, 1 = bf16 C, 2 = fp32 C with rel-pos bias (bf16, stride 256)
//      + 1/sqrt(512) scale.
// ---------------------------------------------------------------------------
template<int EPI>
__global__ __launch_bounds__(256) void mfma_nt(
    const float* __restrict__ A, const unsigned short* __restrict__ B,
    void* __restrict__ Cv,
    int M, int N, int K, int lda, int ldb, int ldc,
    long sA, long sB, long sC,
    const float* __restrict__ relS, long sRel)
{
    __shared__ unsigned short Al[128 * 64];
    __shared__ unsigned short Bl[128 * 64];
    const int tid = threadIdx.x;
    const int lane = tid & 63;
    const int w  = tid >> 6;
    const int wm = w >> 1, wn = w & 1;
    const int fr = lane & 15;
    const int kg = lane >> 4;
    const int m0 = blockIdx.y * 128, n0 = blockIdx.x * 128;
    const int b = blockIdx.z;
    const float* Ab = A + (size_t)b * sA;
    const unsigned short* Bb = B + (size_t)b * sB;

    f32x4 acc[4][4];
#pragma unroll
    for (int i = 0; i < 4; ++i)
#pragma unroll
        for (int j = 0; j < 4; ++j) acc[i][j] = f32x4{0.f, 0.f, 0.f, 0.f};

    for (int k0 = 0; k0 < K; k0 += 64) {
        __syncthreads();
#pragma unroll
        for (int p = 0; p < 4; ++p) {
            int idx = p * 256 + tid;
            int row = idx >> 3;
            int c8  = (idx & 7) * 8;
            gload_lds16(Bb + (size_t)(n0 + row) * ldb + k0 + c8, &Bl[idx * 8]);
        }
#pragma unroll
        for (int p = 0; p < 4; ++p) {
            int idx = p * 256 + tid;
            int row = idx >> 3;
            int c8  = (idx & 7) * 8;
            const float* src = Ab + (size_t)(m0 + row) * lda + k0 + c8;
            float4 f0 = *(const float4*)src;
            float4 f1 = *(const float4*)(src + 4);
            union { unsigned short u[8]; int4 v; } pk;
            pk.u[0] = f2bf(f0.x); pk.u[1] = f2bf(f0.y);
            pk.u[2] = f2bf(f0.z); pk.u[3] = f2bf(f0.w);
            pk.u[4] = f2bf(f1.x); pk.u[5] = f2bf(f1.y);
            pk.u[6] = f2bf(f1.z); pk.u[7] = f2bf(f1.w);
            *(int4*)&Al[idx * 8] = pk.v;
        }
        __syncthreads();
#pragma unroll
        for (int kk = 0; kk < 2; ++kk) {
            s16x8 a[4], bf[4];
#pragma unroll
            for (int mi = 0; mi < 4; ++mi)
                a[mi] = *(const s16x8*)&Al[(wm * 64 + mi * 16 + fr) * 64 + kk * 32 + kg * 8];
#pragma unroll
            for (int ni = 0; ni < 4; ++ni)
                bf[ni] = *(const s16x8*)&Bl[(wn * 64 + ni * 16 + fr) * 64 + kk * 32 + kg * 8];
#pragma unroll
            for (int mi = 0; mi < 4; ++mi)
#pragma unroll
                for (int ni = 0; ni < 4; ++ni)
                    acc[mi][ni] = __builtin_amdgcn_mfma_f32_16x16x32_bf16(
                        a[mi], bf[ni], acc[mi][ni], 0, 0, 0);
        }
    }

    const float scale = 0.044194173824159216f;  // 1/sqrt(512)
#pragma unroll
    for (int mi = 0; mi < 4; ++mi) {
#pragma unroll
        for (int ni = 0; ni < 4; ++ni) {
            int n  = n0 + wn * 64 + ni * 16 + fr;
            int mb = m0 + wm * 64 + mi * 16 + kg * 4;
#pragma unroll
            for (int r = 0; r < 4; ++r) {
                int m = mb + r;
                float v = acc[mi][ni][r];
                if (EPI == 0) {
                    ((float*)Cv)[(size_t)b * sC + (size_t)m * ldc + n] = v;
                } else if (EPI == 1) {
                    ((unsigned short*)Cv)[(size_t)b * sC + (size_t)m * ldc + n] = f2bf(v);
                } else {
                    const unsigned short* rSb = (const unsigned short*)relS + (size_t)b * sRel;
                    int rr = n - m;
                    rr = rr < -KREL ? -KREL : (rr > KREL ? KREL : rr);
                    float bias = bf2f(rSb[(size_t)m * 256 + (rr + KREL)]);
                    ((float*)Cv)[(size_t)b * sC + (size_t)m * ldc + n] = (v + bias) * scale;
                }
            }
        }
    }
}

// ---------------------------------------------------------------------------
// Fused softmax + PV: per block = 64 q-rows x all 512 v-cols of one batch.
// Pass A: online softmax stats (8 threads/row). Main loop (BK=64): stage raw
// scores -> normalize (exp(x-m)/l) -> write fp32 attn in place -> bf16 LDS ->
// MFMA vs vT. Epilogue writes Y = attn @ v.
// 512 threads = 8 waves (2m x 4n), wave tile 32x128.
// ---------------------------------------------------------------------------
__global__ __launch_bounds__(512) void smpv_kernel(
    float* __restrict__ attn,               // [8][2048][2048] raw in, norm out
    const unsigned short* __restrict__ vT,  // [512][16384]
    float* __restrict__ Y)                  // [16384][512]
{
    __shared__ unsigned short Al[64 * 64];
    __shared__ unsigned short Bl[512 * 64];
    __shared__ float sm_m[64], sm_il[64];
    const int tid = threadIdx.x;
    const int b = blockIdx.z;
    const int m0 = blockIdx.x * 64;
    float* abase = attn + (size_t)b * LL * LL;

    // ---- pass A: online row max/sum (8 threads per row) ----
    {
        const int r = tid >> 3, l = tid & 7;
        const float* arow = abase + (size_t)(m0 + r) * LL;
        float m = -1e30f, s = 0.f;
        for (int k = 0; k < 64; ++k) {
            float4 v = ((const float4*)arow)[l + k * 8];
            float mx = fmaxf(fmaxf(v.x, v.y), fmaxf(v.z, v.w));
            float nm = fmaxf(m, mx);
            s = s * __expf(m - nm)
              + __expf(v.x - nm) + __expf(v.y - nm)
              + __expf(v.z - nm) + __expf(v.w - nm);
            m = nm;
        }
#pragma unroll
        for (int o = 1; o < 8; o <<= 1) {
            float om = __shfl_xor(m, o, 8);
            float os = __shfl_xor(s, o, 8);
            float nm = fmaxf(m, om);
            s = s * __expf(m - nm) + os * __expf(om - nm);
            m = nm;
        }
        if (l == 0) { sm_m[r] = m; sm_il[r] = 1.f / s; }
    }

    const int lane = tid & 63;
    const int w  = tid >> 6;
    const int wm = w >> 2, wn = w & 3;   // 2 x 4 waves
    const int fr = lane & 15;
    const int kg = lane >> 4;

    f32x4 acc[2][8];
#pragma unroll
    for (int i = 0; i < 2; ++i)
#pragma unroll
        for (int j = 0; j < 8; ++j) acc[i][j] = f32x4{0.f, 0.f, 0.f, 0.f};

    for (int kt = 0; kt < 32; ++kt) {
        __syncthreads();
        // stage B: vT[512][64] tile
#pragma unroll
        for (int p = 0; p < 8; ++p) {
            int idx = p * 512 + tid;
            int d  = idx >> 3;
            int c8 = (idx & 7) * 8;
            gload_lds16(vT + (size_t)d * 16384 + b * LL + kt * 64 + c8, &Bl[idx * 8]);
        }
        // stage A: raw scores 64x64 -> normalize -> write back + LDS bf16
#pragma unroll
        for (int p = 0; p < 2; ++p) {
            int idx = p * 512 + tid;
            int r  = idx >> 4;
            int c4 = idx & 15;
            float* src = abase + (size_t)(m0 + r) * LL + kt * 64 + c4 * 4;
            float4 v = *(const float4*)src;
            float mm = sm_m[r], il = sm_il[r];
            v.x = __expf(v.x - mm) * il;
            v.y = __expf(v.y - mm) * il;
            v.z = __expf(v.z - mm) * il;
            v.w = __expf(v.w - mm) * il;
            *(float4*)src = v;
            union { unsigned short u[4]; int2 q; } pk;
            pk.u[0] = f2bf(v.x); pk.u[1] = f2bf(v.y);
            pk.u[2] = f2bf(v.z); pk.u[3] = f2bf(v.w);
            *(int2*)&Al[r * 64 + c4 * 4] = pk.q;
        }
        __syncthreads();
#pragma unroll
        for (int kk = 0; kk < 2; ++kk) {
            s16x8 a[2], bf[8];
#pragma unroll
            for (int mi = 0; mi < 2; ++mi)
                a[mi] = *(const s16x8*)&Al[(wm * 32 + mi * 16 + fr) * 64 + kk * 32 + kg * 8];
#pragma unroll
            for (int ni = 0; ni < 8; ++ni)
                bf[ni] = *(const s16x8*)&Bl[(wn * 128 + ni * 16 + fr) * 64 + kk * 32 + kg * 8];
#pragma unroll
            for (int mi = 0; mi < 2; ++mi)
#pragma unroll
                for (int ni = 0; ni < 8; ++ni)
                    acc[mi][ni] = __builtin_amdgcn_mfma_f32_16x16x32_bf16(
                        a[mi], bf[ni], acc[mi][ni], 0, 0, 0);
        }
    }

    // epilogue: Y[b*2048 + m][n]
#pragma unroll
    for (int mi = 0; mi < 2; ++mi) {
#pragma unroll
        for (int ni = 0; ni < 8; ++ni) {
            int n = wn * 128 + ni * 16 + fr;
            int mb = m0 + wm * 32 + mi * 16 + kg * 4;
#pragma unroll
            for (int r = 0; r < 4; ++r) {
                Y[(size_t)(b * LL + mb + r) * DMIN + n] = acc[mi][ni][r];
            }
        }
    }
}

// ---------------------------------------------------------------------------
// Prep kernels.
// ---------------------------------------------------------------------------
__global__ __launch_bounds__(256) void tcast_bf16_512(const float* __restrict__ W,
                                                      unsigned short* __restrict__ WT,
                                                      int R) {
    int i = blockIdx.x * 256 + threadIdx.x;
    if (i >= R * 512) return;
    int r = i >> 9, c = i & 511;
    WT[(size_t)c * R + r] = f2bf(W[i]);
}

__global__ __launch_bounds__(256) void transpose_f32_512(const float* __restrict__ W,
                                                         float* __restrict__ WT) {
    int i = blockIdx.x * 256 + threadIdx.x;
    int r = i >> 9, c = i & 511;
    WT[(size_t)c * 512 + r] = W[i];
}

__global__ __launch_bounds__(256) void cast_bf16_vec(const float* __restrict__ X,
                                                     unsigned short* __restrict__ Xb,
                                                     long n8) {
    long i = (long)blockIdx.x * 256 + threadIdx.x;
    if (i >= n8) return;
    float4 f0 = ((const float4*)X)[2 * i];
    float4 f1 = ((const float4*)X)[2 * i + 1];
    union { unsigned short u[8]; int4 v; } pk;
    pk.u[0] = f2bf(f0.x); pk.u[1] = f2bf(f0.y);
    pk.u[2] = f2bf(f0.z); pk.u[3] = f2bf(f0.w);
    pk.u[4] = f2bf(f1.x); pk.u[5] = f2bf(f1.y);
    pk.u[6] = f2bf(f1.z); pk.u[7] = f2bf(f1.w);
    ((int4*)Xb)[i] = pk.v;
}

__global__ __launch_bounds__(256) void pad_aK_kernel(const float* __restrict__ aK,
                                                     unsigned short* __restrict__ out) {
    int i = blockIdx.x * 256 + threadIdx.x;
    int r = i >> 9;
    out[i] = (r < RR) ? f2bf(aK[i]) : (unsigned short)0;
}

// ---------------------------------------------------------------------------
// rel_attn gather + rel_attn @ aV + fused LayerNorm. 16 rows per block.
// Phase 1: rel[16][129] in LDS. Phase 2: each thread owns 4 rows x 8 d-cols;
// each row is owned by exactly one 64-lane wave -> in-wave LN reductions.
// ---------------------------------------------------------------------------
#define BR 16
__global__ __launch_bounds__(256) void relln_kernel(const float* __restrict__ attn,
                                                    const float* __restrict__ aV,
                                                    float* __restrict__ ctx,
                                                    const float* __restrict__ gamma,
                                                    const float* __restrict__ beta) {
    __shared__ float rel[BR][132];
    const int tid = threadIdx.x;
    const int row0 = blockIdx.x * BR;
    const int g  = tid >> 4;
    const int lt = tid & 15;
    {
        const int row = row0 + g;
        const int i = row & (LL - 1);
        const float* arow = attn + (size_t)row * LL;
        float slow = 0.f, shigh = 0.f;
        const int lo = i - KREL, hi = i + KREL;
#pragma unroll 4
        for (int k = 0; k < 32; ++k) {
            int j4 = lt + k * 16;
            float4 v = ((const float4*)arow)[j4];
            int j = j4 * 4;
            slow  += (j     <= lo ? v.x : 0.f) + (j + 1 <= lo ? v.y : 0.f)
                   + (j + 2 <= lo ? v.z : 0.f) + (j + 3 <= lo ? v.w : 0.f);
            shigh += (j     >= hi ? v.x : 0.f) + (j + 1 >= hi ? v.y : 0.f)
                   + (j + 2 >= hi ? v.z : 0.f) + (j + 3 >= hi ? v.w : 0.f);
        }
#pragma unroll
        for (int o = 1; o < 16; o <<= 1) {
            slow  += __shfl_xor(slow, o, 16);
            shigh += __shfl_xor(shigh, o, 16);
        }
        if (lt == 0) { rel[g][0] = slow; rel[g][128] = shigh; }
        for (int r = 1 + lt; r < 128; r += 16) {
            int j = i + r - KREL;
            rel[g][r] = (j >= 0 && j < LL) ? arow[j] : 0.f;
        }
    }
    __syncthreads();

    const int rw0 = (tid >> 6) * 4;   // wave-uniform
    const int d0 = (tid & 63) * 8;
    float acc[4][8];
#pragma unroll
    for (int a = 0; a < 4; ++a)
#pragma unroll
        for (int d = 0; d < 8; ++d) acc[a][d] = 0.f;

    for (int r = 0; r < RR; ++r) {
        float4 av0 = *(const float4*)&aV[(size_t)r * DMIN + d0];
        float4 av1 = *(const float4*)&aV[(size_t)r * DMIN + d0 + 4];
        float rl[4];
#pragma unroll
        for (int a = 0; a < 4; ++a) rl[a] = rel[rw0 + a][r];
#pragma unroll
        for (int a = 0; a < 4; ++a) {
            acc[a][0] += rl[a] * av0.x; acc[a][1] += rl[a] * av0.y;
            acc[a][2] += rl[a] * av0.z; acc[a][3] += rl[a] * av0.w;
            acc[a][4] += rl[a] * av1.x; acc[a][5] += rl[a] * av1.y;
            acc[a][6] += rl[a] * av1.z; acc[a][7] += rl[a] * av1.w;
        }
    }

    float4 g0 = *(const float4*)&gamma[d0];
    float4 g1 = *(const float4*)&gamma[d0 + 4];
    float4 b0 = *(const float4*)&beta[d0];
    float4 b1 = *(const float4*)&beta[d0 + 4];

#pragma unroll
    for (int a = 0; a < 4; ++a) {
        float* dst = ctx + (size_t)(row0 + rw0 + a) * DMIN + d0;
        float4 c0 = *(float4*)dst;
        float4 c1 = *(float4*)(dst + 4);
        float x[8];
        x[0] = c0.x + acc[a][0]; x[1] = c0.y + acc[a][1];
        x[2] = c0.z + acc[a][2]; x[3] = c0.w + acc[a][3];
        x[4] = c1.x + acc[a][4]; x[5] = c1.y + acc[a][5];
        x[6] = c1.z + acc[a][6]; x[7] = c1.w + acc[a][7];
        float s = 0.f;
#pragma unroll
        for (int d = 0; d < 8; ++d) s += x[d];
#pragma unroll
        for (int o = 32; o; o >>= 1) s += __shfl_xor(s, o, 64);
        float mu = s * (1.f / 512.f);
        float v = 0.f;
#pragma unroll
        for (int d = 0; d < 8; ++d) { x[d] -= mu; v += x[d] * x[d]; }
#pragma unroll
        for (int o = 32; o; o >>= 1) v += __shfl_xor(v, o, 64);
        float inv = rsqrtf(v * (1.f / 512.f) + 1e-5f);
        c0.x = x[0] * inv * g0.x + b0.x; c0.y = x[1] * inv * g0.y + b0.y;
        c0.z = x[2] * inv * g0.z + b0.z; c0.w = x[3] * inv * g0.w + b0.w;
        c1.x = x[4] * inv * g1.x + b1.x; c1.y = x[5] * inv * g1.y + b1.y;
        c1.z = x[6] * inv * g1.z + b1.z; c1.w = x[7] * inv * g1.w + b1.w;
        *(float4*)dst = c0;
        *(float4*)(dst + 4) = c1;
    }
}

// ---------------------------------------------------------------------------
extern "C" void kernel_launch(void* const* d_in, const int* in_sizes, int n_in,
                              void* d_out, int out_size, void* d_ws, size_t ws_size,
                              hipStream_t stream) {
    const float* Xmaj  = (const float*)d_in[0];
    const float* Xmin  = (const float*)d_in[1];
    const float* Wq    = (const float*)d_in[2];
    const float* Wk    = (const float*)d_in[3];
    const float* Wv    = (const float*)d_in[4];
    const float* aK    = (const float*)d_in[5];
    const float* aV    = (const float*)d_in[6];
    const float* gamma = (const float*)d_in[7];
    const float* beta  = (const float*)d_in[8];

    float* Y    = (float*)d_out;                       // [16384, 512] fp32
    float* attn = Y + (size_t)NB * LL * DMIN;          // [8, 2048, 2048] fp32

    // Workspace layout (~112 MB)
    float* q = (float*)d_ws;                                        // [16384,512] f32
    unsigned short* relS_bf = (unsigned short*)(q + (size_t)16384 * 512);  // [16384,256] bf16
    float* WvT = (float*)(relS_bf + (size_t)16384 * 256);           // [512,512] f32
    unsigned short* k_bf    = (unsigned short*)(WvT + 512 * 512);   // [16384,512]
    unsigned short* vT_bf   = k_bf + (size_t)16384 * 512;           // [512,16384]
    unsigned short* Xmin_bf = vT_bf + (size_t)512 * 16384;          // [16384,512]
    unsigned short* WqT_bf  = Xmin_bf + (size_t)16384 * 512;        // [512,1024]
    unsigned short* WkT_bf  = WqT_bf + (size_t)512 * 1024;          // [512,512]
    unsigned short* aK_bf   = WkT_bf + (size_t)512 * 512;           // [256,512]

    const int M = NB * LL;  // 16384
    dim3 blk(256);

    // --- prep ---
    tcast_bf16_512<<<dim3(2048), blk, 0, stream>>>(Wq, WqT_bf, 1024);
    tcast_bf16_512<<<dim3(1024), blk, 0, stream>>>(Wk, WkT_bf, 512);
    transpose_f32_512<<<dim3(1024), blk, 0, stream>>>(Wv, WvT);
    cast_bf16_vec<<<dim3(4096), blk, 0, stream>>>(Xmin, Xmin_bf, (long)M * DMIN / 8);
    pad_aK_kernel<<<dim3(512), blk, 0, stream>>>(aK, aK_bf);

    // --- projections (MFMA) ---
    mfma_nt<0><<<dim3(4, 128, 1), blk, 0, stream>>>(
        Xmaj, WqT_bf, q, M, DMIN, DMAJ, DMAJ, DMAJ, DMIN, 0, 0, 0, nullptr, 0);
    mfma_nt<1><<<dim3(4, 128, 1), blk, 0, stream>>>(
        Xmin, WkT_bf, k_bf, M, DMIN, DMIN, DMIN, DMIN, DMIN, 0, 0, 0, nullptr, 0);
    mfma_nt<1><<<dim3(128, 4, 1), blk, 0, stream>>>(
        WvT, Xmin_bf, vT_bf, DMIN, M, DMIN, DMIN, DMIN, M, 0, 0, 0, nullptr, 0);

    // rel_scores = q @ aK^T -> bf16 [16384,256]
    mfma_nt<1><<<dim3(2, 128, 1), blk, 0, stream>>>(
        q, aK_bf, relS_bf, M, 256, DMIN, DMIN, DMIN, 256, 0, 0, 0, nullptr, 0);

    // raw scores (+rel bias, scale) -> attn region
    mfma_nt<2><<<dim3(16, 16, NB), blk, 0, stream>>>(
        q, k_bf, attn, LL, LL, DMIN, DMIN, DMIN, LL,
        (long)LL * DMIN, (long)LL * DMIN, (long)LL * LL,
        (const float*)relS_bf, (long)LL * 256);

    // fused softmax + PV: normalizes attn in place, writes Y
    smpv_kernel<<<dim3(32, 1, NB), dim3(512), 0, stream>>>(attn, vT_bf, Y);

    // rel_attn @ aV + LayerNorm -> final Y
    relln_kernel<<<dim3(M / BR), blk, 0, stream>>>(attn, aV, Y, gamma, beta);
}